// Round 8
// baseline (2234.734 us; speedup 1.0000x reference)
//
#include <hip/hip_runtime.h>

#define BATCHN 128
#define SEQT   2048
#define FEAT   64
#define UNITS  64
#define NCOL   256   // 4*UNITS gate columns
#define OUTD   6
#define CH     24    // chunk stride in floats (16 data + 8 pad) -> bank offsets {0,24,16,8}
#define BUF    96    // operand buffer stride (4*CH)

typedef float v2f __attribute__((ext_vector_type(2)));

__device__ __forceinline__ float fast_exp2(float x) {
#if __has_builtin(__builtin_amdgcn_exp2f)
    return __builtin_amdgcn_exp2f(x);
#else
    return exp2f(x);
#endif
}
__device__ __forceinline__ float fast_rcp(float x) {
#if __has_builtin(__builtin_amdgcn_rcpf)
    return __builtin_amdgcn_rcpf(x);
#else
    return 1.0f / x;
#endif
}
__device__ __forceinline__ float sig_(float x) {
    return fast_rcp(1.0f + fast_exp2(-1.4426950408889634f * x));
}
__device__ __forceinline__ float tanh_(float x) {
    float xc = fminf(fmaxf(x, -15.0f), 15.0f);
    float e  = fast_exp2(2.8853900817779268f * xc);  // e^(2x)
    return (e - 1.0f) * fast_rcp(e + 1.0f);
}

__device__ __forceinline__ v2f pk_fma(v2f a, v2f b, v2f c) {
    return __builtin_elementwise_fma(a, b, c);
}

template<int CTRL>
__device__ __forceinline__ float dppf(float v) {
    return __builtin_bit_cast(float, __builtin_amdgcn_update_dpp(
        0, __builtin_bit_cast(int, v), CTRL, 0xF, 0xF, true));
}
// reduce both v2f components across 8 consecutive lanes (bits [2:0])
__device__ __forceinline__ v2f red8v(v2f v) {
    v2f t;
    t.x = dppf<0xB1>(v.x);  t.y = dppf<0xB1>(v.y);  v = v + t;  // xor 1
    t.x = dppf<0x4E>(v.x);  t.y = dppf<0x4E>(v.y);  v = v + t;  // xor 2
    t.x = dppf<0x141>(v.x); t.y = dppf<0x141>(v.y); v = v + t;  // xor 4 (RHM)
    return v;
}

__global__ __launch_bounds__(768, 3)
void lstm3_g8p(const float* __restrict__ x,
               const float* __restrict__ W0, const float* __restrict__ U0,
               const float* __restrict__ b0,
               const float* __restrict__ W1, const float* __restrict__ U1,
               const float* __restrict__ b1,
               const float* __restrict__ Wf, const float* __restrict__ bfv,
               const float* __restrict__ Wo, const float* __restrict__ bov,
               float* __restrict__ out)
{
    const int b   = blockIdx.x;
    const int tid = threadIdx.x;   // 0..767
    const int grp = tid >> 8;      // pipeline stage 0,1,2 (layer)
    const int lt  = tid & 255;     // 0..255 within group
    const int cg  = lt >> 3;       // col-group 0..31 (2 units x 4 gates)
    const int kg  = lt & 7;        // k-group 0..7 (16 k each; 0-3 in, 4-7 rec)
    const int up  = kg & 1;        // unit parity this lane activates
    const int myu = 2 * cg + up;   // my unit

    // LDS: lh[g][p] at (2g+p)*BUF ; lx[p] at (6+p)*BUF ; chunk j at +CH*j
    __shared__ __align__(16) float ls[8 * BUF];
    __shared__ float lact[UNITS];
    float* const lsb = ls;

    // ---- weights: 8 cols x 16 k as v2f wt[16][4] (col pair = unit even/odd) --
    const float* Wsel = (grp == 0) ? W0 : W1;
    const float* Usel = (grp == 0) ? U0 : U1;
    const float* bsel = (grp == 0) ? b0 : b1;
    const float* Msel = (kg < 4) ? Wsel : Usel;

    v2f wt[16][4];
    float biasv[4];
#pragma unroll
    for (int g = 0; g < 4; ++g) {
        const int colb = (g << 6) + 2 * cg;
#pragma unroll
        for (int k = 0; k < 16; ++k) {
            const int r = (kg & 3) * 16 + k;
            wt[k][g] = (v2f){Msel[r * NCOL + colb], Msel[r * NCOL + colb + 1]};
        }
        biasv[g] = bsel[(g << 6) + myu];
    }

    // zero h buffers (both parities, all 3 layers)
    if (tid < 6 * BUF) lsb[tid] = 0.f;

    // x staging: 16 loader lanes, depth-2 in-flight registers
    const float* xbase = x + (size_t)b * SEQT * FEAT;
    const bool xload = (grp == 0) && (lt < 16);
    float* xwp0 = lsb + 6 * BUF + CH * (lt >> 2) + 4 * (lt & 3);
    float* xwp1 = xwp0 + BUF;

    float4 xr0, xr1;
    if (xload) {
        *(float4*)xwp1 = *(const float4*)(xbase + lt * 4);              // x(0)
        xr0 = *(const float4*)(xbase + (size_t)1 * FEAT + lt * 4);      // x(1) -> publish @t0
        xr1 = *(const float4*)(xbase + (size_t)2 * FEAT + lt * 4);      // x(2) -> publish @t1
    }
    __syncthreads();

    // per-lane operand chunk pointers, both parities
    const float* inB0 = (grp == 0) ? (lsb + 6 * BUF) : (lsb + (2 * (grp - 1)) * BUF);
    const float* inB1 = inB0 + BUF;
    const float* rcB0 = lsb + (2 * grp) * BUF;
    const float* rcB1 = rcB0 + BUF;
    const int chOff = (kg & 3) * CH;
    const float* opP0 = ((kg < 4) ? inB0 : rcB0) + chOff;
    const float* opP1 = ((kg < 4) ? inB1 : rcB1) + chOff;

    // h write pointers (lanes kg<2 write unit myu)
    float* hwp0 = lsb + (2 * grp) * BUF + CH * (myu >> 4) + (myu & 15);
    float* hwp1 = hwp0 + BUF;

    float c = 0.f;

#define MAC1(V, K)                                                            \
    { v2f s_; s_.x = (V); s_.y = (V);                                         \
      a0 = pk_fma(s_, wt[K][0], a0);                                          \
      a1 = pk_fma(s_, wt[K][1], a1);                                          \
      a2 = pk_fma(s_, wt[K][2], a2);                                          \
      a3 = pk_fma(s_, wt[K][3], a3); }

    // one tick: publish x(TK+1) (loaded 2 ticks ago; vmcnt wait is free),
    // reload the register with x(TK+3), do this group's cell, lgkm-only barrier
#define TICK(TK, PUBW, XR)                                                    \
    {                                                                         \
        if (xload) {                                                          \
            *(float4*)(PUBW) = (XR);                                          \
            int tn = (TK) + 3; if (tn > SEQT - 1) tn = SEQT - 1;              \
            (XR) = *(const float4*)(xbase + (size_t)tn * FEAT + lt * 4);      \
        }                                                                     \
        const int t_ = (TK) - grp;                                            \
        if (t_ >= 0 && t_ < SEQT) {                                           \
            const float* op = ((TK) & 1) ? opP0 : opP1;   /* parity (TK&1)^1 */\
            float4 o0 = *(const float4*)(op);                                 \
            float4 o1 = *(const float4*)(op + 4);                             \
            float4 o2 = *(const float4*)(op + 8);                             \
            float4 o3 = *(const float4*)(op + 12);                            \
            v2f a0 = (v2f){0.f, 0.f}, a1 = a0, a2 = a0, a3 = a0;              \
            MAC1(o0.x, 0)  MAC1(o0.y, 1)  MAC1(o0.z, 2)  MAC1(o0.w, 3)        \
            MAC1(o1.x, 4)  MAC1(o1.y, 5)  MAC1(o1.z, 6)  MAC1(o1.w, 7)        \
            MAC1(o2.x, 8)  MAC1(o2.y, 9)  MAC1(o2.z, 10) MAC1(o2.w, 11)       \
            MAC1(o3.x, 12) MAC1(o3.y, 13) MAC1(o3.z, 14) MAC1(o3.w, 15)       \
            v2f z0 = red8v(a0), z1 = red8v(a1), z2 = red8v(a2), z3 = red8v(a3);\
            const float zi = (up ? z0.y : z0.x) + biasv[0];                   \
            const float zf = (up ? z1.y : z1.x) + biasv[1];                   \
            const float zg = (up ? z2.y : z2.x) + biasv[2];                   \
            const float zo = (up ? z3.y : z3.x) + biasv[3];                   \
            const float ig = sig_(zi), fg = sig_(zf);                         \
            const float gg = tanh_(zg), og = sig_(zo);                        \
            c = fg * c + ig * gg;                                             \
            const float hn = og * tanh_(c);                                   \
            if (kg < 2) *(((TK) & 1) ? hwp1 : hwp0) = hn;                     \
        }                                                                     \
        asm volatile("s_waitcnt lgkmcnt(0)\n\ts_barrier" ::: "memory");       \
    }

    for (int tk = 0; tk < SEQT + 2; tk += 2) {
        TICK(tk,     xwp0, xr0)
        TICK(tk + 1, xwp1, xr1)
    }
#undef TICK
#undef MAC1

    // ---- dense head on final h2 (lh[2] parity 1, chunked) ----
    const float* h2f = lsb + (2 * 2 + 1) * BUF;
    if (tid < UNITS) {
        float a = bfv[tid];
#pragma unroll
        for (int k = 0; k < UNITS; ++k)
            a += h2f[CH * (k >> 4) + (k & 15)] * Wf[k * 64 + tid];
        lact[tid] = fmaxf(a, 0.f);
    }
    __syncthreads();
    if (tid < OUTD) {
        float a = bov[tid];
#pragma unroll
        for (int k = 0; k < UNITS; ++k) a += lact[k] * Wo[k * OUTD + tid];
        out[b * OUTD + tid] = a;
    }
}

extern "C" void kernel_launch(void* const* d_in, const int* in_sizes, int n_in,
                              void* d_out, int out_size, void* d_ws, size_t ws_size,
                              hipStream_t stream) {
    const float* x   = (const float*)d_in[0];
    const float* W0  = (const float*)d_in[1];
    const float* U0  = (const float*)d_in[2];
    const float* b0  = (const float*)d_in[3];
    const float* W1  = (const float*)d_in[4];
    const float* U1  = (const float*)d_in[5];
    const float* b1  = (const float*)d_in[6];
    const float* Wf  = (const float*)d_in[7];
    const float* bfv = (const float*)d_in[8];
    const float* Wo  = (const float*)d_in[9];
    const float* bov = (const float*)d_in[10];
    float* out = (float*)d_out;

    lstm3_g8p<<<BATCHN, 768, 0, stream>>>(x, W0, U0, b0, W1, U1, b1,
                                          Wf, bfv, Wo, bov, out);
}